// Round 4
// baseline (1079.786 us; speedup 1.0000x reference)
//
#include <hip/hip_runtime.h>
#include <hip/hip_bf16.h>

typedef __attribute__((ext_vector_type(8))) short short8;
typedef __attribute__((ext_vector_type(4))) float floatx4;

#define N_ROWS 32768
#define D_DIM  128
#define H_KEYS 8192
#define C_COLS 100
#define BM     64
#define BH     128
#define P_STRIDE  136   // ushorts per P row (272 B, 16B-aligned rows)
#define P_BYTES   (BM * P_STRIDE * 2)   // 17408 B per buffer
#define OL_STRIDE 113   // floats per OL row (odd -> conflict-free epilogue)
#define LOG2E 1.4426950408889634f

__device__ __forceinline__ unsigned short f2bf(float f) {
  union { float f; unsigned int u; } v; v.f = f;
  unsigned int r = v.u + 0x7fffu + ((v.u >> 16) & 1u);  // RNE
  return (unsigned short)(r >> 16);
}

// v_cvt_pk_bf16_f32: two fp32 -> packed bf16
__device__ __forceinline__ unsigned int pk2bf(float a, float b) {
  union { __hip_bfloat162 h; unsigned int u; } c;
  c.h = __float22bfloat162_rn(float2{a, b});
  return c.u;
}

// ---- merged prep: blocks [0,512) pack K (scaled) + ksq; [512,768) pack V ----
__global__ void prep_kernel(const float* __restrict__ keys,
                            const float* __restrict__ values,
                            const float* __restrict__ temp,
                            unsigned short* __restrict__ kp,
                            float* __restrict__ ksq,
                            unsigned short* __restrict__ vp) {
  int tid = threadIdx.x;
  if (blockIdx.x < 512) {
    // K pack: block rt = blockIdx.x covers key rows [16rt, 16rt+16).
    // thread = (c, lane): dst[(rt*4+c)*64+lane][j] = s*K[16rt+(lane&15)][32c+(lane>>4)*8+j]
    __shared__ float red[256];
    int rt = blockIdx.x;
    int lane = tid & 63;
    int c = tid >> 6;
    float scale = 2.0f * LOG2E / temp[0];
    int row = rt * 16 + (lane & 15);
    int d0 = c * 32 + (lane >> 4) * 8;
    const float* s = keys + (size_t)row * D_DIM + d0;
    float4 lo = *(const float4*)s;
    float4 hi = *(const float4*)(s + 4);
    float sq = lo.x*lo.x + lo.y*lo.y + lo.z*lo.z + lo.w*lo.w
             + hi.x*hi.x + hi.y*hi.y + hi.z*hi.z + hi.w*hi.w;
    red[c * 64 + lane] = sq;
    union { short8 v; unsigned int u[4]; } cv;
    cv.u[0] = pk2bf(lo.x * scale, lo.y * scale);
    cv.u[1] = pk2bf(lo.z * scale, lo.w * scale);
    cv.u[2] = pk2bf(hi.x * scale, hi.y * scale);
    cv.u[3] = pk2bf(hi.z * scale, hi.w * scale);
    *(short8*)(kp + ((size_t)(rt * 4 + c) * 64 + lane) * 8) = cv.v;
    __syncthreads();
    if (tid < 16) {
      float acc = 0.f;
#pragma unroll
      for (int cc = 0; cc < 4; ++cc)
#pragma unroll
        for (int q = 0; q < 4; ++q)
          acc += red[cc * 64 + q * 16 + tid];
      ksq[rt * 16 + tid] = -acc * LOG2E / temp[0];
    }
  } else {
    // V pack: 112-col pad with ones-column at col 100 (denominator trick)
    __shared__ float vt[32 * 113];
    int g = blockIdx.x - 512;
    for (int idx = tid; idx < 32 * 112; idx += 256) {
      int k = idx / 112, col = idx - k * 112;
      float val;
      if (col < C_COLS) val = values[(size_t)(g * 32 + k) * C_COLS + col];
      else val = (col == C_COLS) ? 1.0f : 0.0f;
      vt[k * 113 + col] = val;
    }
    __syncthreads();
    for (int u = tid; u < 7 * 64; u += 256) {
      int ct = u >> 6, l = u & 63;
      int n0 = l & 15, q = l >> 4;
      short8 o;
#pragma unroll
      for (int j = 0; j < 8; ++j) o[j] = (short)f2bf(vt[(q * 8 + j) * 113 + ct * 16 + n0]);
      *(short8*)(vp + ((size_t)(g * 7 + ct) * 64 + l) * 8) = o;
    }
  }
}

// Fused RBF attention, 2-way key split for occupancy (4 blocks/CU).
// blockIdx: b = >>1 (row block), kb = &1 (key half: iters [32kb, 32kb+32)).
// kb==0 writes numerator to d_out + den to denA; kb==1 to outB/denB.
__global__ __launch_bounds__(256, 4)
void attn_rbf_kernel(const float* __restrict__ x,
                     const unsigned short* __restrict__ kp,
                     const float* __restrict__ ksq,
                     const unsigned short* __restrict__ vp,
                     float* __restrict__ outA, float* __restrict__ denA,
                     float* __restrict__ outB, float* __restrict__ denB) {
  __shared__ __align__(16) char smem[2 * P_BYTES];  // 34816 B; epilogue OL aliases front
  float* OL = (float*)smem;

  const int tid = threadIdx.x;
  const int w = tid >> 6;       // wave 0..3
  const int lane = tid & 63;
  const int n0 = lane & 15;
  const int q = lane >> 4;
  const int b = blockIdx.x >> 1;
  const int kb = blockIdx.x & 1;

  // x rows for this block (fp32 row-major) -> bf16 B-fragments in registers.
  short8 xf[4][4];
#pragma unroll
  for (int rt = 0; rt < 4; ++rt)
#pragma unroll
    for (int c = 0; c < 4; ++c) {
      const float* s = x + (size_t)(b * 64 + rt * 16 + n0) * D_DIM + c * 32 + q * 8;
      float4 lo = *(const float4*)s;
      float4 hi = *(const float4*)(s + 4);
      union { short8 v; unsigned int u[4]; } cv;
      cv.u[0] = pk2bf(lo.x, lo.y);
      cv.u[1] = pk2bf(lo.z, lo.w);
      cv.u[2] = pk2bf(hi.x, hi.y);
      cv.u[3] = pk2bf(hi.z, hi.w);
      xf[rt][c] = cv.v;
    }

  floatx4 oacc[4][2];
#pragma unroll
  for (int rt = 0; rt < 4; ++rt)
#pragma unroll
    for (int u = 0; u < 2; ++u)
      oacc[rt][u] = (floatx4){0.f, 0.f, 0.f, 0.f};

  const int nct = (w < 3) ? 2 : 1;  // waves own C-tiles {0,1},{2,3},{4,5},{6}
  const int ct0 = w * 2;

  const int it0 = kb * 32;
  for (int ii = 0; ii < 32; ++ii) {
    const int it = it0 + ii;
    unsigned short* P = (unsigned short*)(smem + (ii & 1) * P_BYTES);

    // ---- global prefetch (L2-resident streams) ----
    short8 kf[2][4];
#pragma unroll
    for (int kt = 0; kt < 2; ++kt)
#pragma unroll
      for (int c = 0; c < 4; ++c)
        kf[kt][c] = *(const short8*)(kp + ((size_t)((it * 8 + w * 2 + kt) * 4 + c) * 64 + lane) * 8);

    floatx4 ksq4[2];
#pragma unroll
    for (int kt = 0; kt < 2; ++kt)
      ksq4[kt] = *(const floatx4*)(ksq + it * BH + w * 32 + kt * 16 + q * 4);

    short8 vf[4][2];
#pragma unroll
    for (int c = 0; c < 4; ++c)
#pragma unroll
      for (int u = 0; u < 2; ++u)
        if (u < nct)
          vf[c][u] = *(const short8*)(vp + ((size_t)((it * 4 + c) * 7 + (ct0 + u)) * 64 + lane) * 8);

    // ---- S^T = K . X^T, C-init = -ksq*log2e/T (folded bias) ----
#pragma unroll
    for (int kt = 0; kt < 2; ++kt) {
      floatx4 s[4];
#pragma unroll
      for (int rt = 0; rt < 4; ++rt) s[rt] = ksq4[kt];
#pragma unroll
      for (int c = 0; c < 4; ++c)
#pragma unroll
        for (int rt = 0; rt < 4; ++rt)
          s[rt] = __builtin_amdgcn_mfma_f32_16x16x32_bf16(kf[kt][c], xf[rt][c], s[rt], 0, 0, 0);
#pragma unroll
      for (int rt = 0; rt < 4; ++rt) {
        uint2 pk;
        pk.x = pk2bf(__builtin_amdgcn_exp2f(s[rt][0]), __builtin_amdgcn_exp2f(s[rt][1]));
        pk.y = pk2bf(__builtin_amdgcn_exp2f(s[rt][2]), __builtin_amdgcn_exp2f(s[rt][3]));
        *(uint2*)(P + (rt * 16 + n0) * P_STRIDE + w * 32 + kt * 16 + q * 4) = pk;
      }
    }
    __syncthreads();  // single barrier: P complete; next iter writes other buffer

    // ---- O += P . V ----
#pragma unroll
    for (int c = 0; c < 4; ++c) {
      short8 pf[4];
#pragma unroll
      for (int rt = 0; rt < 4; ++rt)
        pf[rt] = *(const short8*)(P + (rt * 16 + n0) * P_STRIDE + c * 32 + q * 8);
#pragma unroll
      for (int u = 0; u < 2; ++u)
        if (u < nct)
#pragma unroll
          for (int rt = 0; rt < 4; ++rt)
            oacc[rt][u] = __builtin_amdgcn_mfma_f32_16x16x32_bf16(pf[rt], vf[c][u], oacc[rt][u], 0, 0, 0);
    }
  }
  __syncthreads();  // all waves done reading P before OL overlays it

  // ---- epilogue: stage fp32 tile in LDS, write unnormalized partial ----
#pragma unroll
  for (int rt = 0; rt < 4; ++rt)
#pragma unroll
    for (int u = 0; u < 2; ++u)
      if (u < nct)
#pragma unroll
        for (int i = 0; i < 4; ++i)
          OL[(rt * 16 + q * 4 + i) * OL_STRIDE + (ct0 + u) * 16 + n0] = oacc[rt][u][i];
  __syncthreads();

  float* dst  = kb ? outB : outA;
  float* dden = kb ? denB : denA;
  float* dstb = dst + (size_t)b * (BM * C_COLS);
  for (int idx = tid; idx < BM * C_COLS; idx += 256) {
    int n = idx / C_COLS;
    int cc = idx - n * C_COLS;
    dstb[idx] = OL[n * OL_STRIDE + cc];
  }
  if (tid < BM) dden[b * BM + tid] = OL[tid * OL_STRIDE + 100];
}

// out = (outA + outB) / (denA + denB), float4 over 25 vec4 per 100-col row
__global__ void combine_kernel(float* __restrict__ outA,
                               const float* __restrict__ outB,
                               const float* __restrict__ denA,
                               const float* __restrict__ denB) {
  int v = blockIdx.x * 256 + threadIdx.x;     // float4 index
  int n = v / 25;                             // row
  float4 a = *(const float4*)(outA + (size_t)v * 4);
  float4 bb = *(const float4*)(outB + (size_t)v * 4);
  float r = 1.0f / (denA[n] + denB[n]);
  float4 o;
  o.x = (a.x + bb.x) * r; o.y = (a.y + bb.y) * r;
  o.z = (a.z + bb.z) * r; o.w = (a.w + bb.w) * r;
  *(float4*)(outA + (size_t)v * 4) = o;
}

extern "C" void kernel_launch(void* const* d_in, const int* in_sizes, int n_in,
                              void* d_out, int out_size, void* d_ws, size_t ws_size,
                              hipStream_t stream) {
  (void)in_sizes; (void)n_in; (void)out_size; (void)ws_size;
  const float* x      = (const float*)d_in[0];
  const float* keys   = (const float*)d_in[1];
  const float* values = (const float*)d_in[2];
  const float* temp   = (const float*)d_in[3];
  float* out = (float*)d_out;

  char* ws = (char*)d_ws;
  unsigned short* kp  = (unsigned short*)(ws);             // 2,097,152 B
  unsigned short* vp  = (unsigned short*)(ws + 2097152);   // 1,835,008 B
  float*          ksq = (float*)(ws + 3932160);            //    32,768 B
  float*          denA= (float*)(ws + 3964928);            //   131,072 B
  float*          denB= (float*)(ws + 4096000);            //   131,072 B
  float*          outB= (float*)(ws + 4227072);            // 13,107,200 B (tot ~17.3 MB)

  hipLaunchKernelGGL(prep_kernel,     dim3(768),   dim3(256), 0, stream,
                     keys, values, temp, kp, ksq, vp);
  hipLaunchKernelGGL(attn_rbf_kernel, dim3(1024),  dim3(256), 0, stream,
                     x, kp, ksq, vp, out, denA, outB, denB);
  hipLaunchKernelGGL(combine_kernel,  dim3(3200),  dim3(256), 0, stream,
                     out, outB, denA, denB);
}

// Round 5
// 737.612 us; speedup vs baseline: 1.4639x; 1.4639x over previous
//
#include <hip/hip_runtime.h>
#include <hip/hip_bf16.h>

typedef __attribute__((ext_vector_type(8))) short short8;
typedef __attribute__((ext_vector_type(4))) float floatx4;

#define N_ROWS 32768
#define D_DIM  128
#define H_KEYS 8192
#define C_COLS 100
#define BM     64
#define BH     128
#define P_STRIDE  136   // ushorts per P row (272 B, 16B-aligned rows)
#define P_BYTES   (BM * P_STRIDE * 2)   // 17408 B per buffer
#define OL_STRIDE 113   // floats per OL row (odd -> conflict-free epilogue)
#define LOG2E 1.4426950408889634f

__device__ __forceinline__ unsigned short f2bf(float f) {
  union { float f; unsigned int u; } v; v.f = f;
  unsigned int r = v.u + 0x7fffu + ((v.u >> 16) & 1u);  // RNE
  return (unsigned short)(r >> 16);
}

// v_cvt_pk_bf16_f32: two fp32 -> packed bf16
__device__ __forceinline__ unsigned int pk2bf(float a, float b) {
  union { __hip_bfloat162 h; unsigned int u; } c;
  c.h = __float22bfloat162_rn(float2{a, b});
  return c.u;
}

// ---- merged prep: blocks [0,512) pack K (scaled) + ksq; [512,768) pack V ----
__global__ void prep_kernel(const float* __restrict__ keys,
                            const float* __restrict__ values,
                            const float* __restrict__ temp,
                            unsigned short* __restrict__ kp,
                            float* __restrict__ ksq,
                            unsigned short* __restrict__ vp) {
  int tid = threadIdx.x;
  if (blockIdx.x < 512) {
    // K pack: block rt covers key rows [16rt, 16rt+16).
    __shared__ float red[256];
    int rt = blockIdx.x;
    int lane = tid & 63;
    int c = tid >> 6;
    float scale = 2.0f * LOG2E / temp[0];
    int row = rt * 16 + (lane & 15);
    int d0 = c * 32 + (lane >> 4) * 8;
    const float* s = keys + (size_t)row * D_DIM + d0;
    float4 lo = *(const float4*)s;
    float4 hi = *(const float4*)(s + 4);
    float sq = lo.x*lo.x + lo.y*lo.y + lo.z*lo.z + lo.w*lo.w
             + hi.x*hi.x + hi.y*hi.y + hi.z*hi.z + hi.w*hi.w;
    red[c * 64 + lane] = sq;
    union { short8 v; unsigned int u[4]; } cv;
    cv.u[0] = pk2bf(lo.x * scale, lo.y * scale);
    cv.u[1] = pk2bf(lo.z * scale, lo.w * scale);
    cv.u[2] = pk2bf(hi.x * scale, hi.y * scale);
    cv.u[3] = pk2bf(hi.z * scale, hi.w * scale);
    *(short8*)(kp + ((size_t)(rt * 4 + c) * 64 + lane) * 8) = cv.v;
    __syncthreads();
    if (tid < 16) {
      float acc = 0.f;
#pragma unroll
      for (int cc = 0; cc < 4; ++cc)
#pragma unroll
        for (int q = 0; q < 4; ++q)
          acc += red[cc * 64 + q * 16 + tid];
      ksq[rt * 16 + tid] = -acc * LOG2E / temp[0];
    }
  } else {
    // V pack: 112-col pad with ones-column at col 100 (denominator trick)
    __shared__ float vt[32 * 113];
    int g = blockIdx.x - 512;
    for (int idx = tid; idx < 32 * 112; idx += 256) {
      int k = idx / 112, col = idx - k * 112;
      float val;
      if (col < C_COLS) val = values[(size_t)(g * 32 + k) * C_COLS + col];
      else val = (col == C_COLS) ? 1.0f : 0.0f;
      vt[k * 113 + col] = val;
    }
    __syncthreads();
    for (int u = tid; u < 7 * 64; u += 256) {
      int ct = u >> 6, l = u & 63;
      int n0 = l & 15, q = l >> 4;
      short8 o;
#pragma unroll
      for (int j = 0; j < 8; ++j) o[j] = (short)f2bf(vt[(q * 8 + j) * 113 + ct * 16 + n0]);
      *(short8*)(vp + ((size_t)(g * 7 + ct) * 64 + l) * 8) = o;
    }
  }
}

// Fused RBF attention, 3-way key split (grid 1536 = 2 full rounds at 3 blocks/CU).
// blockIdx: b = /3 (row block), kb = %3 (key chunk: iters {[0,22),[22,43),[43,64)}).
// Writes unnormalized partial numerator + denominator per chunk.
__global__ __launch_bounds__(256, 3)
void attn_rbf_kernel(const float* __restrict__ x,
                     const unsigned short* __restrict__ kp,
                     const float* __restrict__ ksq,
                     const unsigned short* __restrict__ vp,
                     float* __restrict__ outA, float* __restrict__ denA,
                     float* __restrict__ outB, float* __restrict__ denB,
                     float* __restrict__ outC, float* __restrict__ denC) {
  __shared__ __align__(16) char smem[2 * P_BYTES];  // 34816 B; epilogue OL aliases front
  float* OL = (float*)smem;

  const int tid = threadIdx.x;
  const int w = tid >> 6;       // wave 0..3
  const int lane = tid & 63;
  const int n0 = lane & 15;
  const int q = lane >> 4;
  const int b = blockIdx.x / 3;
  const int kb = blockIdx.x - b * 3;

  // x rows for this block (fp32 row-major) -> bf16 B-fragments in registers.
  short8 xf[4][4];
#pragma unroll
  for (int rt = 0; rt < 4; ++rt)
#pragma unroll
    for (int c = 0; c < 4; ++c) {
      const float* s = x + (size_t)(b * 64 + rt * 16 + n0) * D_DIM + c * 32 + q * 8;
      float4 lo = *(const float4*)s;
      float4 hi = *(const float4*)(s + 4);
      union { short8 v; unsigned int u[4]; } cv;
      cv.u[0] = pk2bf(lo.x, lo.y);
      cv.u[1] = pk2bf(lo.z, lo.w);
      cv.u[2] = pk2bf(hi.x, hi.y);
      cv.u[3] = pk2bf(hi.z, hi.w);
      xf[rt][c] = cv.v;
    }

  floatx4 oacc[4][2];
#pragma unroll
  for (int rt = 0; rt < 4; ++rt)
#pragma unroll
    for (int u = 0; u < 2; ++u)
      oacc[rt][u] = (floatx4){0.f, 0.f, 0.f, 0.f};

  const int nct = (w < 3) ? 2 : 1;  // waves own C-tiles {0,1},{2,3},{4,5},{6}
  const int ct0 = w * 2;

  const int it0  = (kb == 0) ? 0 : (kb == 1 ? 22 : 43);
  const int itn  = (kb == 0) ? 22 : 21;
  for (int ii = 0; ii < itn; ++ii) {
    const int it = it0 + ii;
    unsigned short* P = (unsigned short*)(smem + (ii & 1) * P_BYTES);

    // ---- global prefetch (L2-resident streams) ----
    short8 kf[2][4];
#pragma unroll
    for (int kt = 0; kt < 2; ++kt)
#pragma unroll
      for (int c = 0; c < 4; ++c)
        kf[kt][c] = *(const short8*)(kp + ((size_t)((it * 8 + w * 2 + kt) * 4 + c) * 64 + lane) * 8);

    floatx4 ksq4[2];
#pragma unroll
    for (int kt = 0; kt < 2; ++kt)
      ksq4[kt] = *(const floatx4*)(ksq + it * BH + w * 32 + kt * 16 + q * 4);

    short8 vf[4][2];
#pragma unroll
    for (int c = 0; c < 4; ++c)
#pragma unroll
      for (int u = 0; u < 2; ++u)
        if (u < nct)
          vf[c][u] = *(const short8*)(vp + ((size_t)((it * 4 + c) * 7 + (ct0 + u)) * 64 + lane) * 8);

    // ---- S^T = K . X^T, C-init = -ksq*log2e/T (folded bias) ----
#pragma unroll
    for (int kt = 0; kt < 2; ++kt) {
      floatx4 s[4];
#pragma unroll
      for (int rt = 0; rt < 4; ++rt) s[rt] = ksq4[kt];
#pragma unroll
      for (int c = 0; c < 4; ++c)
#pragma unroll
        for (int rt = 0; rt < 4; ++rt)
          s[rt] = __builtin_amdgcn_mfma_f32_16x16x32_bf16(kf[kt][c], xf[rt][c], s[rt], 0, 0, 0);
#pragma unroll
      for (int rt = 0; rt < 4; ++rt) {
        uint2 pk;
        pk.x = pk2bf(__builtin_amdgcn_exp2f(s[rt][0]), __builtin_amdgcn_exp2f(s[rt][1]));
        pk.y = pk2bf(__builtin_amdgcn_exp2f(s[rt][2]), __builtin_amdgcn_exp2f(s[rt][3]));
        *(uint2*)(P + (rt * 16 + n0) * P_STRIDE + w * 32 + kt * 16 + q * 4) = pk;
      }
    }
    __syncthreads();  // single barrier: P complete; next iter writes other buffer

    // ---- O += P . V ----
#pragma unroll
    for (int c = 0; c < 4; ++c) {
      short8 pf[4];
#pragma unroll
      for (int rt = 0; rt < 4; ++rt)
        pf[rt] = *(const short8*)(P + (rt * 16 + n0) * P_STRIDE + c * 32 + q * 8);
#pragma unroll
      for (int u = 0; u < 2; ++u)
        if (u < nct)
#pragma unroll
          for (int rt = 0; rt < 4; ++rt)
            oacc[rt][u] = __builtin_amdgcn_mfma_f32_16x16x32_bf16(pf[rt], vf[c][u], oacc[rt][u], 0, 0, 0);
    }
  }
  __syncthreads();  // all waves done reading P before OL overlays it

  // ---- epilogue: stage fp32 tile in LDS, write unnormalized partial ----
#pragma unroll
  for (int rt = 0; rt < 4; ++rt)
#pragma unroll
    for (int u = 0; u < 2; ++u)
      if (u < nct)
#pragma unroll
        for (int i = 0; i < 4; ++i)
          OL[(rt * 16 + q * 4 + i) * OL_STRIDE + (ct0 + u) * 16 + n0] = oacc[rt][u][i];
  __syncthreads();

  float* dst  = (kb == 0) ? outA : (kb == 1 ? outB : outC);
  float* dden = (kb == 0) ? denA : (kb == 1 ? denB : denC);
  float* dstb = dst + (size_t)b * (BM * C_COLS);
  for (int idx = tid; idx < BM * C_COLS; idx += 256) {
    int n = idx / C_COLS;
    int cc = idx - n * C_COLS;
    dstb[idx] = OL[n * OL_STRIDE + cc];
  }
  if (tid < BM) dden[b * BM + tid] = OL[tid * OL_STRIDE + 100];
}

// out = (outA + outB + outC) / (denA + denB + denC), float4 (25 vec4 per row)
__global__ void combine_kernel(float* __restrict__ outA,
                               const float* __restrict__ outB,
                               const float* __restrict__ outC,
                               const float* __restrict__ denA,
                               const float* __restrict__ denB,
                               const float* __restrict__ denC) {
  int v = blockIdx.x * 256 + threadIdx.x;     // float4 index
  int n = v / 25;                             // row
  float4 a  = *(const float4*)(outA + (size_t)v * 4);
  float4 bb = *(const float4*)(outB + (size_t)v * 4);
  float4 cc = *(const float4*)(outC + (size_t)v * 4);
  float r = 1.0f / (denA[n] + denB[n] + denC[n]);
  float4 o;
  o.x = (a.x + bb.x + cc.x) * r; o.y = (a.y + bb.y + cc.y) * r;
  o.z = (a.z + bb.z + cc.z) * r; o.w = (a.w + bb.w + cc.w) * r;
  *(float4*)(outA + (size_t)v * 4) = o;
}

extern "C" void kernel_launch(void* const* d_in, const int* in_sizes, int n_in,
                              void* d_out, int out_size, void* d_ws, size_t ws_size,
                              hipStream_t stream) {
  (void)in_sizes; (void)n_in; (void)out_size; (void)ws_size;
  const float* x      = (const float*)d_in[0];
  const float* keys   = (const float*)d_in[1];
  const float* values = (const float*)d_in[2];
  const float* temp   = (const float*)d_in[3];
  float* out = (float*)d_out;

  char* ws = (char*)d_ws;
  unsigned short* kp  = (unsigned short*)(ws);              //  2,097,152 B
  unsigned short* vp  = (unsigned short*)(ws + 2097152);    //  1,835,008 B
  float*          ksq = (float*)(ws + 3932160);             //     32,768 B
  float*          denA= (float*)(ws + 3964928);             //    131,072 B
  float*          denB= (float*)(ws + 4096000);             //    131,072 B
  float*          denC= (float*)(ws + 4227072);             //    131,072 B
  float*          outB= (float*)(ws + 4358144);             // 13,107,200 B
  float*          outC= (float*)(ws + 17465344);            // 13,107,200 B (tot ~30.6 MB)

  hipLaunchKernelGGL(prep_kernel,     dim3(768),   dim3(256), 0, stream,
                     keys, values, temp, kp, ksq, vp);
  hipLaunchKernelGGL(attn_rbf_kernel, dim3(1536),  dim3(256), 0, stream,
                     x, kp, ksq, vp, out, denA, outB, denB, outC, denC);
  hipLaunchKernelGGL(combine_kernel,  dim3(3200),  dim3(256), 0, stream,
                     out, outB, outC, denA, denB, denC);
}

// Round 6
// 210.982 us; speedup vs baseline: 5.1179x; 3.4961x over previous
//
#include <hip/hip_runtime.h>
#include <hip/hip_bf16.h>

typedef __attribute__((ext_vector_type(8))) short short8;
typedef __attribute__((ext_vector_type(4))) float floatx4;

#define N_ROWS 32768
#define D_DIM  128
#define H_KEYS 8192
#define C_COLS 100
#define BM     64
#define BH     128
#define P_STRIDE  136   // ushorts per P row (272 B, 16B-aligned rows)
#define P_BYTES   (BM * P_STRIDE * 2)   // 17408 B per buffer
#define OL_STRIDE 113   // floats per OL row (odd -> conflict-free epilogue)
#define LOG2E 1.4426950408889634f

// NOTE (hard-won): __launch_bounds__(256, w) caps VGPRs at 256/w on this
// toolchain (empirical: w=2 -> 108 used OK; w=3 -> cap 84 -> spill; w=4 ->
// cap 64 -> spill, GBs of scratch traffic). Keep w=2; at 108 VGPR the HW
// still gives 4 waves/SIMD, so 4 blocks/CU happen at runtime via the grid.

__device__ __forceinline__ unsigned short f2bf(float f) {
  union { float f; unsigned int u; } v; v.f = f;
  unsigned int r = v.u + 0x7fffu + ((v.u >> 16) & 1u);  // RNE
  return (unsigned short)(r >> 16);
}

// v_cvt_pk_bf16_f32: two fp32 -> packed bf16
__device__ __forceinline__ unsigned int pk2bf(float a, float b) {
  union { __hip_bfloat162 h; unsigned int u; } c;
  c.h = __float22bfloat162_rn(float2{a, b});
  return c.u;
}

// ---- merged prep: blocks [0,512) pack K (scaled) + ksq; [512,768) pack V ----
__global__ void prep_kernel(const float* __restrict__ keys,
                            const float* __restrict__ values,
                            const float* __restrict__ temp,
                            unsigned short* __restrict__ kp,
                            float* __restrict__ ksq,
                            unsigned short* __restrict__ vp) {
  int tid = threadIdx.x;
  if (blockIdx.x < 512) {
    // K pack: block rt covers key rows [16rt, 16rt+16).
    __shared__ float red[256];
    int rt = blockIdx.x;
    int lane = tid & 63;
    int c = tid >> 6;
    float scale = 2.0f * LOG2E / temp[0];
    int row = rt * 16 + (lane & 15);
    int d0 = c * 32 + (lane >> 4) * 8;
    const float* s = keys + (size_t)row * D_DIM + d0;
    float4 lo = *(const float4*)s;
    float4 hi = *(const float4*)(s + 4);
    float sq = lo.x*lo.x + lo.y*lo.y + lo.z*lo.z + lo.w*lo.w
             + hi.x*hi.x + hi.y*hi.y + hi.z*hi.z + hi.w*hi.w;
    red[c * 64 + lane] = sq;
    union { short8 v; unsigned int u[4]; } cv;
    cv.u[0] = pk2bf(lo.x * scale, lo.y * scale);
    cv.u[1] = pk2bf(lo.z * scale, lo.w * scale);
    cv.u[2] = pk2bf(hi.x * scale, hi.y * scale);
    cv.u[3] = pk2bf(hi.z * scale, hi.w * scale);
    *(short8*)(kp + ((size_t)(rt * 4 + c) * 64 + lane) * 8) = cv.v;
    __syncthreads();
    if (tid < 16) {
      float acc = 0.f;
#pragma unroll
      for (int cc = 0; cc < 4; ++cc)
#pragma unroll
        for (int q = 0; q < 4; ++q)
          acc += red[cc * 64 + q * 16 + tid];
      ksq[rt * 16 + tid] = -acc * LOG2E / temp[0];
    }
  } else {
    // V pack: 112-col pad with ones-column at col 100 (denominator trick)
    __shared__ float vt[32 * 113];
    int g = blockIdx.x - 512;
    for (int idx = tid; idx < 32 * 112; idx += 256) {
      int k = idx / 112, col = idx - k * 112;
      float val;
      if (col < C_COLS) val = values[(size_t)(g * 32 + k) * C_COLS + col];
      else val = (col == C_COLS) ? 1.0f : 0.0f;
      vt[k * 113 + col] = val;
    }
    __syncthreads();
    for (int u = tid; u < 7 * 64; u += 256) {
      int ct = u >> 6, l = u & 63;
      int n0 = l & 15, q = l >> 4;
      short8 o;
#pragma unroll
      for (int j = 0; j < 8; ++j) o[j] = (short)f2bf(vt[(q * 8 + j) * 113 + ct * 16 + n0]);
      *(short8*)(vp + ((size_t)(g * 7 + ct) * 64 + l) * 8) = o;
    }
  }
}

// Fused RBF attention, 2-way key split: grid 1024 = one fully-resident round
// at 4 blocks/CU. blockIdx: b = >>1 (row block), kb = &1 (key half).
// Writes unnormalized partial numerator + denominator per half.
__global__ __launch_bounds__(256, 2)
void attn_rbf_kernel(const float* __restrict__ x,
                     const unsigned short* __restrict__ kp,
                     const float* __restrict__ ksq,
                     const unsigned short* __restrict__ vp,
                     float* __restrict__ outA, float* __restrict__ denA,
                     float* __restrict__ outB, float* __restrict__ denB) {
  __shared__ __align__(16) char smem[2 * P_BYTES];  // 34816 B; epilogue OL aliases front
  float* OL = (float*)smem;

  const int tid = threadIdx.x;
  const int w = tid >> 6;       // wave 0..3
  const int lane = tid & 63;
  const int n0 = lane & 15;
  const int q = lane >> 4;
  const int b = blockIdx.x >> 1;
  const int kb = blockIdx.x & 1;

  // x rows for this block (fp32 row-major) -> bf16 B-fragments in registers.
  short8 xf[4][4];
#pragma unroll
  for (int rt = 0; rt < 4; ++rt)
#pragma unroll
    for (int c = 0; c < 4; ++c) {
      const float* s = x + (size_t)(b * 64 + rt * 16 + n0) * D_DIM + c * 32 + q * 8;
      float4 lo = *(const float4*)s;
      float4 hi = *(const float4*)(s + 4);
      union { short8 v; unsigned int u[4]; } cv;
      cv.u[0] = pk2bf(lo.x, lo.y);
      cv.u[1] = pk2bf(lo.z, lo.w);
      cv.u[2] = pk2bf(hi.x, hi.y);
      cv.u[3] = pk2bf(hi.z, hi.w);
      xf[rt][c] = cv.v;
    }

  floatx4 oacc[4][2];
#pragma unroll
  for (int rt = 0; rt < 4; ++rt)
#pragma unroll
    for (int u = 0; u < 2; ++u)
      oacc[rt][u] = (floatx4){0.f, 0.f, 0.f, 0.f};

  const int nct = (w < 3) ? 2 : 1;  // waves own C-tiles {0,1},{2,3},{4,5},{6}
  const int ct0 = w * 2;

  const int it0 = kb * 32;
  for (int ii = 0; ii < 32; ++ii) {
    const int it = it0 + ii;
    unsigned short* P = (unsigned short*)(smem + (ii & 1) * P_BYTES);

    // ---- global prefetch (L2-resident streams) ----
    short8 kf[2][4];
#pragma unroll
    for (int kt = 0; kt < 2; ++kt)
#pragma unroll
      for (int c = 0; c < 4; ++c)
        kf[kt][c] = *(const short8*)(kp + ((size_t)((it * 8 + w * 2 + kt) * 4 + c) * 64 + lane) * 8);

    floatx4 ksq4[2];
#pragma unroll
    for (int kt = 0; kt < 2; ++kt)
      ksq4[kt] = *(const floatx4*)(ksq + it * BH + w * 32 + kt * 16 + q * 4);

    short8 vf[4][2];
#pragma unroll
    for (int c = 0; c < 4; ++c)
#pragma unroll
      for (int u = 0; u < 2; ++u)
        if (u < nct)
          vf[c][u] = *(const short8*)(vp + ((size_t)((it * 4 + c) * 7 + (ct0 + u)) * 64 + lane) * 8);

    // ---- S^T = K . X^T, C-init = -ksq*log2e/T (folded bias) ----
#pragma unroll
    for (int kt = 0; kt < 2; ++kt) {
      floatx4 s[4];
#pragma unroll
      for (int rt = 0; rt < 4; ++rt) s[rt] = ksq4[kt];
#pragma unroll
      for (int c = 0; c < 4; ++c)
#pragma unroll
        for (int rt = 0; rt < 4; ++rt)
          s[rt] = __builtin_amdgcn_mfma_f32_16x16x32_bf16(kf[kt][c], xf[rt][c], s[rt], 0, 0, 0);
#pragma unroll
      for (int rt = 0; rt < 4; ++rt) {
        uint2 pk;
        pk.x = pk2bf(__builtin_amdgcn_exp2f(s[rt][0]), __builtin_amdgcn_exp2f(s[rt][1]));
        pk.y = pk2bf(__builtin_amdgcn_exp2f(s[rt][2]), __builtin_amdgcn_exp2f(s[rt][3]));
        *(uint2*)(P + (rt * 16 + n0) * P_STRIDE + w * 32 + kt * 16 + q * 4) = pk;
      }
    }
    __syncthreads();  // single barrier: P complete; next iter writes other buffer

    // ---- O += P . V ----
#pragma unroll
    for (int c = 0; c < 4; ++c) {
      short8 pf[4];
#pragma unroll
      for (int rt = 0; rt < 4; ++rt)
        pf[rt] = *(const short8*)(P + (rt * 16 + n0) * P_STRIDE + c * 32 + q * 8);
#pragma unroll
      for (int u = 0; u < 2; ++u)
        if (u < nct)
#pragma unroll
          for (int rt = 0; rt < 4; ++rt)
            oacc[rt][u] = __builtin_amdgcn_mfma_f32_16x16x32_bf16(pf[rt], vf[c][u], oacc[rt][u], 0, 0, 0);
    }
  }
  __syncthreads();  // all waves done reading P before OL overlays it

  // ---- epilogue: stage fp32 tile in LDS, write unnormalized partial ----
#pragma unroll
  for (int rt = 0; rt < 4; ++rt)
#pragma unroll
    for (int u = 0; u < 2; ++u)
      if (u < nct)
#pragma unroll
        for (int i = 0; i < 4; ++i)
          OL[(rt * 16 + q * 4 + i) * OL_STRIDE + (ct0 + u) * 16 + n0] = oacc[rt][u][i];
  __syncthreads();

  float* dst  = kb ? outB : outA;
  float* dden = kb ? denB : denA;
  float* dstb = dst + (size_t)b * (BM * C_COLS);
  for (int idx = tid; idx < BM * C_COLS; idx += 256) {
    int n = idx / C_COLS;
    int cc = idx - n * C_COLS;
    dstb[idx] = OL[n * OL_STRIDE + cc];
  }
  if (tid < BM) dden[b * BM + tid] = OL[tid * OL_STRIDE + 100];
}

// out = (outA + outB) / (denA + denB), float4 over 25 vec4 per 100-col row
__global__ void combine_kernel(float* __restrict__ outA,
                               const float* __restrict__ outB,
                               const float* __restrict__ denA,
                               const float* __restrict__ denB) {
  int v = blockIdx.x * 256 + threadIdx.x;     // float4 index
  int n = v / 25;                             // row
  float4 a  = *(const float4*)(outA + (size_t)v * 4);
  float4 bb = *(const float4*)(outB + (size_t)v * 4);
  float r = 1.0f / (denA[n] + denB[n]);
  float4 o;
  o.x = (a.x + bb.x) * r; o.y = (a.y + bb.y) * r;
  o.z = (a.z + bb.z) * r; o.w = (a.w + bb.w) * r;
  *(float4*)(outA + (size_t)v * 4) = o;
}

extern "C" void kernel_launch(void* const* d_in, const int* in_sizes, int n_in,
                              void* d_out, int out_size, void* d_ws, size_t ws_size,
                              hipStream_t stream) {
  (void)in_sizes; (void)n_in; (void)out_size; (void)ws_size;
  const float* x      = (const float*)d_in[0];
  const float* keys   = (const float*)d_in[1];
  const float* values = (const float*)d_in[2];
  const float* temp   = (const float*)d_in[3];
  float* out = (float*)d_out;

  char* ws = (char*)d_ws;
  unsigned short* kp  = (unsigned short*)(ws);              //  2,097,152 B
  unsigned short* vp  = (unsigned short*)(ws + 2097152);    //  1,835,008 B
  float*          ksq = (float*)(ws + 3932160);             //     32,768 B
  float*          denA= (float*)(ws + 3964928);             //    131,072 B
  float*          denB= (float*)(ws + 4096000);             //    131,072 B
  float*          outB= (float*)(ws + 4227072);             // 13,107,200 B (tot ~17.3 MB)

  hipLaunchKernelGGL(prep_kernel,     dim3(768),   dim3(256), 0, stream,
                     keys, values, temp, kp, ksq, vp);
  hipLaunchKernelGGL(attn_rbf_kernel, dim3(1024),  dim3(256), 0, stream,
                     x, kp, ksq, vp, out, denA, outB, denB);
  hipLaunchKernelGGL(combine_kernel,  dim3(3200),  dim3(256), 0, stream,
                     out, outB, denA, denB);
}